// Round 1
// baseline (448.596 us; speedup 1.0000x reference)
//
#include <hip/hip_runtime.h>
#include <math.h>

// DSSIM (mean) over B=32, C=3, H=W=512 fp32 images, 11x11 Gaussian blur.
// Strategy: separable blur (recover 1D kernel from supplied 2D), fused
// per-tile kernel: global->LDS raw tiles -> register-blocked h-blur of the
// 5 quantities (x1, x2, x1^2, x2^2, x1x2) -> LDS -> register-blocked v-blur
// -> SSIM -> block reduction -> atomicAdd partial into d_ws -> finalize.

namespace {
constexpr int IMG_H = 512, IMG_W = 512;
constexpr int TW = 64, TH = 32;           // output tile per block
constexpr int RH = TH + 10;               // 42 raw rows (halo 5 each side)
constexpr int RW = TW + 10;               // 74 raw cols
constexpr int SR = 76;                    // padded LDS row stride (16B-aligned rows)
constexpr int NIMG = 96;                  // 32*3
constexpr int TILES = (IMG_W / TW) * (IMG_H / TH); // 8*16 = 128
constexpr float C1c = 1e-4f;              // 0.01^2
constexpr float C2c = 9e-4f;              // 0.03^2
constexpr float INV_N = 1.0f / 25165824.0f; // 1/(32*3*512*512)
}

__global__ void dssim_zero(float* ws) { ws[0] = 0.0f; }

__global__ void dssim_final(const float* __restrict__ ws, float* __restrict__ out) {
  out[0] = ws[0] * INV_N;
}

__global__ __launch_bounds__(256, 2) void dssim_main(
    const float* __restrict__ im1, const float* __restrict__ im2,
    const float* __restrict__ gk, float* __restrict__ ws)
{
  __shared__ float sA[RH * SR];          // raw image1 tile  (12768 B)
  __shared__ float sB[RH * SR];          // raw image2 tile  (12768 B)
  __shared__ float sH[5][RH * TW];       // h-blurred 5 quantities (53760 B)
  __shared__ float sred[4];

  const int tid = threadIdx.x;
  const int bid = blockIdx.x;
  const int img  = bid >> 7;             // /128 tiles per image
  const int tile = bid & 127;
  const int tx = tile & 7;               // 0..7
  const int ty = tile >> 3;              // 0..15

  const float* __restrict__ p1 = im1 + (size_t)img * (IMG_H * IMG_W);
  const float* __restrict__ p2 = im2 + (size_t)img * (IMG_H * IMG_W);

  // Recover separable 1D weights from the 2D kernel (channel 0):
  // k2d[i][j] = k1[i]*k1[j] with sum(k1)=1  =>  k1[i] = k2d[i][5]/sqrt(k2d[5][5])
  float wt[11];
  {
    float ic = 1.0f / sqrtf(gk[5 * 11 + 5]);
    #pragma unroll
    for (int i = 0; i < 11; ++i) wt[i] = gk[i * 11 + 5] * ic;
  }

  // ---- Phase 1: global -> LDS raw tiles (zero-padded SAME borders) ----
  const int gx0 = tx * TW - 5, gy0 = ty * TH - 5;
  for (int i = tid; i < RH * RW; i += 256) {
    int r = i / RW, c = i - r * RW;
    int gy = gy0 + r, gx = gx0 + c;
    float v1 = 0.f, v2 = 0.f;
    if ((unsigned)gy < (unsigned)IMG_H && (unsigned)gx < (unsigned)IMG_W) {
      int off = gy * IMG_W + gx;
      v1 = p1[off];
      v2 = p2[off];
    }
    sA[r * SR + c] = v1;
    sB[r * SR + c] = v2;
  }
  __syncthreads();

  // ---- Phase 2: horizontal blur of 5 quantities, 8 outputs per task ----
  // task t: row r (0..41), x-group xg (0..7) -> outputs cols xg*8 .. xg*8+7
  for (int t = tid; t < RH * 8; t += 256) {
    int r = t >> 3, xg = t & 7;
    int base = r * SR + xg * 8;          // 16B-aligned (SR=76, xg*8 floats)
    float a[18], b[18];
    #pragma unroll
    for (int i = 0; i < 18; ++i) { a[i] = sA[base + i]; b[i] = sB[base + i]; }
    float o0[8], o1[8], o2[8], o3[8], o4[8];
    #pragma unroll
    for (int j = 0; j < 8; ++j) {
      float m1 = 0.f, m2 = 0.f, q1 = 0.f, q2 = 0.f, q3 = 0.f;
      #pragma unroll
      for (int k = 0; k < 11; ++k) {
        float w = wt[k], xa = a[j + k], xb = b[j + k];
        float wxa = w * xa;
        m1 = fmaf(w, xa, m1);
        m2 = fmaf(w, xb, m2);
        q1 = fmaf(wxa, xa, q1);
        q2 = fmaf(w * xb, xb, q2);
        q3 = fmaf(wxa, xb, q3);
      }
      o0[j] = m1; o1[j] = m2; o2[j] = q1; o3[j] = q2; o4[j] = q3;
    }
    int ob = r * TW + xg * 8;            // 16B-aligned -> ds_write_b128 merge
    #pragma unroll
    for (int j = 0; j < 8; ++j) sH[0][ob + j] = o0[j];
    #pragma unroll
    for (int j = 0; j < 8; ++j) sH[1][ob + j] = o1[j];
    #pragma unroll
    for (int j = 0; j < 8; ++j) sH[2][ob + j] = o2[j];
    #pragma unroll
    for (int j = 0; j < 8; ++j) sH[3][ob + j] = o3[j];
    #pragma unroll
    for (int j = 0; j < 8; ++j) sH[4][ob + j] = o4[j];
  }
  __syncthreads();

  // ---- Phase 3: vertical blur (8 rows/thread) + SSIM + reduce ----
  const int x  = tid & 63;
  const int y0 = (tid >> 6) * 8;         // 4 row-groups of 8
  float acc[5][8];
  #pragma unroll
  for (int q = 0; q < 5; ++q)
    #pragma unroll
    for (int j = 0; j < 8; ++j) acc[q][j] = 0.f;

  #pragma unroll
  for (int q = 0; q < 5; ++q) {
    #pragma unroll
    for (int rr = 0; rr < 18; ++rr) {
      float v = sH[q][(y0 + rr) * TW + x];
      #pragma unroll
      for (int j = 0; j < 8; ++j) {
        int k = rr - j;
        if (k >= 0 && k < 11) acc[q][j] = fmaf(wt[k], v, acc[q][j]);
      }
    }
  }

  float lsum = 0.f;
  #pragma unroll
  for (int j = 0; j < 8; ++j) {
    float mu1 = acc[0][j], mu2 = acc[1][j];
    float e11 = acc[2][j], e22 = acc[3][j], e12 = acc[4][j];
    float mu1sq = mu1 * mu1, mu2sq = mu2 * mu2, mu12 = mu1 * mu2;
    float s11 = e11 - mu1sq, s22 = e22 - mu2sq, s12 = e12 - mu12;
    float num = (2.f * mu12 + C1c) * (2.f * s12 + C2c);
    float den = (mu1sq + mu2sq + C1c) * (s11 + s22 + C2c);
    float ssim = num / den;
    lsum += (1.f - ssim) * 0.5f;
  }

  // wave (64) shuffle reduce, then cross-wave via LDS, one atomic per block
  #pragma unroll
  for (int off = 32; off > 0; off >>= 1) lsum += __shfl_down(lsum, off);
  if ((tid & 63) == 0) sred[tid >> 6] = lsum;
  __syncthreads();
  if (tid == 0) atomicAdd(ws, sred[0] + sred[1] + sred[2] + sred[3]);
}

extern "C" void kernel_launch(void* const* d_in, const int* in_sizes, int n_in,
                              void* d_out, int out_size, void* d_ws, size_t ws_size,
                              hipStream_t stream) {
  const float* im1 = (const float*)d_in[0];
  const float* im2 = (const float*)d_in[1];
  const float* gk  = (const float*)d_in[2];
  float* out = (float*)d_out;
  float* ws  = (float*)d_ws;

  hipLaunchKernelGGL(dssim_zero, dim3(1), dim3(1), 0, stream, ws);
  hipLaunchKernelGGL(dssim_main, dim3(NIMG * TILES), dim3(256), 0, stream,
                     im1, im2, gk, ws);
  hipLaunchKernelGGL(dssim_final, dim3(1), dim3(1), 0, stream, ws, out);
}